// Round 8
// baseline (220.267 us; speedup 1.0000x reference)
//
#include <hip/hip_runtime.h>
#include <hip/hip_bf16.h>

typedef __attribute__((ext_vector_type(8))) short short8;
typedef __attribute__((ext_vector_type(4))) float v4f;
typedef __attribute__((ext_vector_type(16))) float v16f;

// async global->LDS, 16B per lane. LDS dest must be wave-uniform base + lane*16.
#define ASYNC_COPY16(ldsptr, gptr)                                                        \
  __builtin_amdgcn_global_load_lds((const __attribute__((address_space(1))) void*)(gptr), \
                                   (__attribute__((address_space(3))) void*)(ldsptr),     \
                                   16, 0, 0)

__device__ __forceinline__ unsigned short f2bf(float f) {
  unsigned int u = __float_as_uint(f);
  u += 0x7fffu + ((u >> 16) & 1u);  // RNE
  return (unsigned short)(u >> 16);
}
__device__ __forceinline__ float bf2f(unsigned short s) {
  return __uint_as_float(((unsigned int)s) << 16);
}

// ---------------- fused fp32 -> bf16 convert for all three inputs ----------------
__global__ void convert_all(const float* __restrict__ h, const float* __restrict__ wq,
                            const float* __restrict__ wo, unsigned short* __restrict__ ho,
                            unsigned short* __restrict__ wqo, unsigned short* __restrict__ woo) {
  int i = (blockIdx.x * blockDim.x + threadIdx.x) * 4;
  const float* src;
  unsigned short* dst;
  int j;
  if (i < 4194304) { src = h; dst = ho; j = i; }
  else if (i < 7340032) { src = wq; dst = wqo; j = i - 4194304; }
  else { src = wo; dst = woo; j = i - 7340032; }
  float4 v = *(const float4*)(src + j);
  ushort4 o;
  o.x = f2bf(v.x); o.y = f2bf(v.y); o.z = f2bf(v.z); o.w = f2bf(v.w);
  *(ushort4*)(dst + j) = o;
}

// ---------------- bf16 GEMM, C[m][n] = sum_k A[m][k]*B[n][k] ----------------
// 128xBN block tile, BK=32, 4 waves each 64x(BN/2). Optional bf16 output.
template <int BN, bool BF16OUT>
__global__ __launch_bounds__(256) void gemm_bt(const unsigned short* __restrict__ A,
                                               const unsigned short* __restrict__ Bm,
                                               void* __restrict__ Cv, int M, int N, int K) {
  constexpr int WN = BN / 2;   // per-wave n extent
  constexpr int JN = WN / 16;  // 16-col tiles per wave
  __shared__ __attribute__((aligned(16))) unsigned short As[128 * 32];
  __shared__ __attribute__((aligned(16))) unsigned short Bs[BN * 32];
  int t = threadIdx.x;
  int w = t >> 6, lane = t & 63, kb = lane >> 4, lr = lane & 15;
  int m0 = blockIdx.y * 128, n0 = blockIdx.x * BN;
  int wm = (w >> 1) * 64, wn = (w & 1) * WN;
  v4f acc[4][JN];
#pragma unroll
  for (int i = 0; i < 4; i++)
#pragma unroll
    for (int j = 0; j < JN; j++) acc[i][j] = (v4f){0.f, 0.f, 0.f, 0.f};
  int ra = m0 + (t >> 2);
  int rb = n0 + (t >> 2);
  int ca = (t & 3) * 8;
  for (int k0 = 0; k0 < K; k0 += 32) {
    ASYNC_COPY16(&As[t * 8],        A + (size_t)ra * K + k0 + ca);
    ASYNC_COPY16(&As[2048 + t * 8], A + (size_t)(ra + 64) * K + k0 + ca);
#pragma unroll
    for (int c = 0; c < BN / 64; c++)
      ASYNC_COPY16(&Bs[c * 2048 + t * 8], Bm + (size_t)(rb + c * 64) * K + k0 + ca);
    __syncthreads();
    short8 av[4], bv[JN];
#pragma unroll
    for (int i = 0; i < 4; i++) av[i] = *(const short8*)&As[(wm + i * 16 + lr) * 32 + kb * 8];
#pragma unroll
    for (int j = 0; j < JN; j++) bv[j] = *(const short8*)&Bs[(wn + j * 16 + lr) * 32 + kb * 8];
#pragma unroll
    for (int i = 0; i < 4; i++)
#pragma unroll
      for (int j = 0; j < JN; j++)
        acc[i][j] = __builtin_amdgcn_mfma_f32_16x16x32_bf16(av[i], bv[j], acc[i][j], 0, 0, 0);
    __syncthreads();
  }
  // C/D layout: col = lane&15, row = (lane>>4)*4 + reg
#pragma unroll
  for (int i = 0; i < 4; i++) {
    int row = m0 + wm + i * 16 + kb * 4;
#pragma unroll
    for (int j = 0; j < JN; j++) {
      int col = n0 + wn + j * 16 + lr;
#pragma unroll
      for (int r = 0; r < 4; r++) {
        if (BF16OUT)
          ((unsigned short*)Cv)[(size_t)(row + r) * N + col] = f2bf(acc[i][j][r]);
        else
          ((float*)Cv)[(size_t)(row + r) * N + col] = acc[i][j][r];
      }
    }
  }
}

// ------- fused RoPE + head split (q, v, k thirds!) + V transpose, bf16 qkv in -------
// Q pre-scaled by (1/sqrt(HD)) * log2(e). Outputs: Q,K [bh][s][64], Vt [bh][d][s].
__global__ __launch_bounds__(256) void rope_vt(const unsigned short* __restrict__ qkv,
                                               unsigned short* __restrict__ Q,
                                               unsigned short* __restrict__ Ko,
                                               unsigned short* __restrict__ Vt) {
  __shared__ float tile[64][65];
  int t = threadIdx.x;
  int bh = blockIdx.y, s0 = blockIdx.x * 64;
  int b = bh >> 4, h = bh & 15;
  int mp = h >> 1, ii = h & 1;
  int hbase = mp * 384 + ii * 64;  // q at +0, v at +128, k at +256
  int tx = t & 63, ty = t >> 6;
#pragma unroll
  for (int q16 = 0; q16 < 16; q16++) {
    int srow = q16 * 4 + ty;
    tile[srow][tx] = bf2f(qkv[(size_t)(b * 2048 + s0 + srow) * 3072 + hbase + 128 + tx]);
  }
  // RoPE on q,k: thread t -> s row t>>2, 16-dim chunk t&3
  int sl = t >> 2, ch = t & 3;
  int s = s0 + sl;
  size_t ib = (size_t)(b * 2048 + s) * 3072 + hbase + ch * 16;
  short8 qv0 = *(const short8*)(qkv + ib);
  short8 qv1 = *(const short8*)(qkv + ib + 8);
  short8 kv0 = *(const short8*)(qkv + ib + 256);
  short8 kv1 = *(const short8*)(qkv + ib + 264);
  float qf[16], kf[16];
#pragma unroll
  for (int j = 0; j < 8; j++) {
    qf[j] = bf2f((unsigned short)qv0[j]); qf[8 + j] = bf2f((unsigned short)qv1[j]);
    kf[j] = bf2f((unsigned short)kv0[j]); kf[8 + j] = bf2f((unsigned short)kv1[j]);
  }
  if (ch < 2) {  // rotary pairs j = ch*8+jj < 16
#pragma unroll
    for (int jj = 0; jj < 8; jj++) {
      int j = ch * 8 + jj;
      float ang = (float)s * expf(-(float)j * 0.57564627324851142f);
      float sn, cs;
      sincosf(ang, &sn, &cs);
      float a = qf[2 * jj], bq = qf[2 * jj + 1];
      qf[2 * jj] = a * cs - bq * sn; qf[2 * jj + 1] = bq * cs + a * sn;
      float c2 = kf[2 * jj], d2 = kf[2 * jj + 1];
      kf[2 * jj] = c2 * cs - d2 * sn; kf[2 * jj + 1] = d2 * cs + c2 * sn;
    }
  }
  const float qs = 0.125f * 1.4426950408889634f;  // 1/sqrt(64) * log2(e)
  unsigned short qo[16], ko[16];
#pragma unroll
  for (int j = 0; j < 16; j++) { qo[j] = f2bf(qs * qf[j]); ko[j] = f2bf(kf[j]); }
  size_t ob = (size_t)(bh * 2048 + s) * 64 + ch * 16;
  *(short8*)(Q + ob) = *(short8*)qo;
  *(short8*)(Q + ob + 8) = *(short8*)(qo + 8);
  *(short8*)(Ko + ob) = *(short8*)ko;
  *(short8*)(Ko + ob + 8) = *(short8*)(ko + 8);
  __syncthreads();
#pragma unroll
  for (int q16 = 0; q16 < 16; q16++) {
    int drow = q16 * 4 + ty;
    Vt[(size_t)bh * 64 * 2048 + (size_t)drow * 2048 + s0 + tx] = f2bf(tile[tx][drow]);
  }
}

// ---------------- fused causal flash attention, v8: 32x32x16 MFMA, S^T path ----------
// Per block: 4 waves x 32 q-rows = 128 q-rows, 64-key tiles (nkt = 2*qtile+2).
// S^T orientation: S^T = K.Q^T (A=K m=key, B=Q n=q), then O^T = V^T.P^T (A=V^T
// m=d, B=P^T n=q). Q is loop-invariant in regs; P round-trips LDS per wave
// ([q][key] stride 68, b64 packed writes, b128 B-frag reads). One shfl_xor(32)
// finishes the l-sum. 32x32 C/D mapping: col=lane&31, row=(reg&3)+8*(reg>>2)
// +4*(lane>>5) [m74/m101]. LDS 49 KB; 512 blocks = 2/CU; dbuf async staging.
__global__ __launch_bounds__(256, 2) void attn_fused(const unsigned short* __restrict__ Qg,
                                                     const unsigned short* __restrict__ Kg,
                                                     const unsigned short* __restrict__ Vtg,
                                                     unsigned short* __restrict__ AO) {
  __shared__ __attribute__((aligned(16))) unsigned short Ks[2 * 4096];  // [buf][c8][key64][8]
  __shared__ __attribute__((aligned(16))) unsigned short Vs[2 * 4096];  // [buf][c8][d64][8]
  __shared__ __attribute__((aligned(16))) unsigned short Ps[4 * 32 * 68];  // [w][q32][68]
  int t = threadIdx.x;
  int w = t >> 6, lane = t & 63, l31 = lane & 31, hh = lane >> 5;
  int gid = blockIdx.x;
  int bh = gid >> 4;
  // qtile swizzle: co-resident blocks (gid, gid+256) differ by 8 -> no resonance
  int qtile = ((gid & 15) + (gid >> 4) + ((gid >> 8) << 3)) & 15;
  int m0 = qtile * 128;
  const unsigned short* Qb = Qg + (size_t)bh * 2048 * 64;
  const unsigned short* Kb = Kg + (size_t)bh * 2048 * 64;
  const unsigned short* Vb = Vtg + (size_t)bh * 64 * 2048;

  int qrow = m0 + w * 32 + l31;  // this lane's q (B-frag n = lane&31)
  // Q B-fragments, loop-invariant: B[k=dim][n=q]: dims kc*16 + hh*8 + j
  short8 qf[4];
#pragma unroll
  for (int kc = 0; kc < 4; kc++)
    qf[kc] = *(const short8*)(Qb + (size_t)qrow * 64 + kc * 16 + hh * 8);

  v16f acc0, acc1;
#pragma unroll
  for (int r = 0; r < 16; r++) { acc0[r] = 0.f; acc1[r] = 0.f; }
  float lp = 0.f;

  int nkt = 2 * qtile + 2;

  // stage 64-key K/V tile: Ks[c][key] <- K[kt*64+key][c*8..], Vs[c][d] <- Vt[d][kt*64+c*8..]
  auto stage = [&](int kt, int buf) {
    int base = buf * 4096;
#pragma unroll
    for (int rep = 0; rep < 2; rep++) {
      int s = rep * 256 + t;
      int c = s >> 6, rr = s & 63;
      ASYNC_COPY16(&Ks[base + s * 8], Kb + (size_t)(kt * 64 + rr) * 64 + c * 8);
      ASYNC_COPY16(&Vs[base + s * 8], Vb + (size_t)rr * 2048 + kt * 64 + c * 8);
    }
  };

  stage(0, 0);
  __syncthreads();

  unsigned short* Pq = &Ps[(w * 32 + l31) * 68];  // my q-row in P
  for (int kt = 0; kt < nkt; kt++) {
    int cur = (kt & 1) * 4096;
    if (kt + 1 < nkt) stage(kt + 1, (kt + 1) & 1);  // prefetch overlaps compute
    // ---- S^T = K.Q^T : per key-group kg (32 keys), contraction over 64 dims ----
    v16f sc[2];
#pragma unroll
    for (int kg = 0; kg < 2; kg++) {
      v16f z;
#pragma unroll
      for (int r = 0; r < 16; r++) z[r] = 0.f;
#pragma unroll
      for (int kc = 0; kc < 4; kc++) {
        short8 kf = *(const short8*)&Ks[cur + ((2 * kc + hh) * 64 + kg * 32 + l31) * 8];
        z = __builtin_amdgcn_mfma_f32_32x32x16_bf16(kf, qf[kc], z, 0, 0, 0);
      }
      sc[kg] = z;
    }
    if (kt * 64 + 63 > m0 + w * 32) {  // tile may cross diagonal (wave-uniform)
#pragma unroll
      for (int kg = 0; kg < 2; kg++)
#pragma unroll
        for (int r = 0; r < 16; r++) {
          int key = kt * 64 + kg * 32 + (r & 3) + 8 * (r >> 2) + 4 * hh;
          if (key > qrow) sc[kg][r] = -1e30f;
        }
    }
    // ---- exp2 + packed b64 P stores: keys kg*32 + qd*8 + hh*4 + (0..3) ----
#pragma unroll
    for (int kg = 0; kg < 2; kg++)
#pragma unroll
      for (int qd = 0; qd < 4; qd++) {
        unsigned short pk[4];
#pragma unroll
        for (int r = 0; r < 4; r++) {
          float p = exp2f(sc[kg][qd * 4 + r]);
          lp += p;
          pk[r] = f2bf(p);
        }
        *(uint2*)&Pq[kg * 32 + qd * 8 + hh * 4] = *(uint2*)pk;
      }
    // ---- O^T += V^T.P^T : contraction over 64 keys (4 chunks of 16) ----
#pragma unroll
    for (int kc = 0; kc < 4; kc++) {
      short8 pf = *(const short8*)&Pq[kc * 16 + hh * 8];
      short8 vf0 = *(const short8*)&Vs[cur + ((2 * kc + hh) * 64 + l31) * 8];
      short8 vf1 = *(const short8*)&Vs[cur + ((2 * kc + hh) * 64 + 32 + l31) * 8];
      acc0 = __builtin_amdgcn_mfma_f32_32x32x16_bf16(vf0, pf, acc0, 0, 0, 0);
      acc1 = __builtin_amdgcn_mfma_f32_32x32x16_bf16(vf1, pf, acc1, 0, 0, 0);
    }
    __syncthreads();  // all waves done with cur; prefetch drained
  }
  // ---- l-sum: lanes l and l+32 hold complementary key subsets of q=l31 ----
  lp += __shfl_xor(lp, 32);
  float inv = 1.0f / lp;
  int b = bh >> 4, h = bh & 15;
  size_t obase = (size_t)(b * 2048 + qrow) * 1024 + h * 64;
#pragma unroll
  for (int qd = 0; qd < 4; qd++) {
    unsigned short o0[4], o1[4];
#pragma unroll
    for (int r = 0; r < 4; r++) {
      o0[r] = f2bf(acc0[qd * 4 + r] * inv);
      o1[r] = f2bf(acc1[qd * 4 + r] * inv);
    }
    int d0 = qd * 8 + hh * 4;
    *(uint2*)&AO[obase + d0] = *(uint2*)o0;         // dt=0: dims 0..31
    *(uint2*)&AO[obase + 32 + d0] = *(uint2*)o1;    // dt=1: dims 32..63
  }
}

extern "C" void kernel_launch(void* const* d_in, const int* in_sizes, int n_in,
                              void* d_out, int out_size, void* d_ws, size_t ws_size,
                              hipStream_t stream) {
  const float* hidden = (const float*)d_in[0];
  const float* w_qkv = (const float*)d_in[1];
  const float* w_out = (const float*)d_in[2];
  float* out = (float*)d_out;
  char* ws = (char*)d_ws;
  unsigned short* hid_bf = (unsigned short*)(ws);                  //  8 MB
  unsigned short* wqkv_bf = (unsigned short*)(ws + (8ull << 20));  //  6 MB
  unsigned short* wout_bf = (unsigned short*)(ws + (14ull << 20)); //  2 MB
  unsigned short* qkv_bf = (unsigned short*)(ws + (16ull << 20));  // 24 MB
  unsigned short* Qb = (unsigned short*)(ws + (40ull << 20));      //  8 MB
  unsigned short* Kb = (unsigned short*)(ws + (48ull << 20));      //  8 MB
  unsigned short* Vt = (unsigned short*)(ws + (56ull << 20));      //  8 MB
  unsigned short* AO = (unsigned short*)(ws + (64ull << 20));      //  8 MB

  convert_all<<<8192, 256, 0, stream>>>(hidden, w_qkv, w_out, hid_bf, wqkv_bf, wout_bf);
  // qkv = hidden @ w_qkv.T  (M=4096, N=3072, K=1024), bf16 out
  gemm_bt<128, true><<<dim3(24, 32), 256, 0, stream>>>(hid_bf, wqkv_bf, qkv_bf, 4096, 3072, 1024);
  rope_vt<<<dim3(32, 32), 256, 0, stream>>>(qkv_bf, Qb, Kb, Vt);
  attn_fused<<<512, 256, 0, stream>>>(Qb, Kb, Vt, AO);
  // out = attn_out @ w_out.T  (M=4096, N=1024, K=1024), fp32 out, 128x64 tiles
  gemm_bt<64, false><<<dim3(16, 32), 256, 0, stream>>>(AO, wout_bf, out, 4096, 1024, 1024);
}

// Round 9
// 207.000 us; speedup vs baseline: 1.0641x; 1.0641x over previous
//
#include <hip/hip_runtime.h>
#include <hip/hip_bf16.h>

typedef __attribute__((ext_vector_type(8))) short short8;
typedef __attribute__((ext_vector_type(4))) float v4f;

// async global->LDS, 16B per lane. LDS dest must be wave-uniform base + lane*16.
#define ASYNC_COPY16(ldsptr, gptr)                                                        \
  __builtin_amdgcn_global_load_lds((const __attribute__((address_space(1))) void*)(gptr), \
                                   (__attribute__((address_space(3))) void*)(ldsptr),     \
                                   16, 0, 0)

__device__ __forceinline__ unsigned short f2bf(float f) {
  unsigned int u = __float_as_uint(f);
  u += 0x7fffu + ((u >> 16) & 1u);  // RNE
  return (unsigned short)(u >> 16);
}
__device__ __forceinline__ float bf2f(unsigned short s) {
  return __uint_as_float(((unsigned int)s) << 16);
}

// ---------------- fused fp32 -> bf16 convert for all three inputs ----------------
__global__ void convert_all(const float* __restrict__ h, const float* __restrict__ wq,
                            const float* __restrict__ wo, unsigned short* __restrict__ ho,
                            unsigned short* __restrict__ wqo, unsigned short* __restrict__ woo) {
  int i = (blockIdx.x * blockDim.x + threadIdx.x) * 4;
  const float* src;
  unsigned short* dst;
  int j;
  if (i < 4194304) { src = h; dst = ho; j = i; }
  else if (i < 7340032) { src = wq; dst = wqo; j = i - 4194304; }
  else { src = wo; dst = woo; j = i - 7340032; }
  float4 v = *(const float4*)(src + j);
  ushort4 o;
  o.x = f2bf(v.x); o.y = f2bf(v.y); o.z = f2bf(v.z); o.w = f2bf(v.w);
  *(ushort4*)(dst + j) = o;
}

// ---------------- bf16 GEMM, C[m][n] = sum_k A[m][k]*B[n][k] ----------------
// 128xBN block tile, BK=32, 4 waves each 64x(BN/2). Optional bf16 output.
template <int BN, bool BF16OUT>
__global__ __launch_bounds__(256) void gemm_bt(const unsigned short* __restrict__ A,
                                               const unsigned short* __restrict__ Bm,
                                               void* __restrict__ Cv, int M, int N, int K) {
  constexpr int WN = BN / 2;   // per-wave n extent
  constexpr int JN = WN / 16;  // 16-col tiles per wave
  __shared__ __attribute__((aligned(16))) unsigned short As[128 * 32];
  __shared__ __attribute__((aligned(16))) unsigned short Bs[BN * 32];
  int t = threadIdx.x;
  int w = t >> 6, lane = t & 63, kb = lane >> 4, lr = lane & 15;
  int m0 = blockIdx.y * 128, n0 = blockIdx.x * BN;
  int wm = (w >> 1) * 64, wn = (w & 1) * WN;
  v4f acc[4][JN];
#pragma unroll
  for (int i = 0; i < 4; i++)
#pragma unroll
    for (int j = 0; j < JN; j++) acc[i][j] = (v4f){0.f, 0.f, 0.f, 0.f};
  int ra = m0 + (t >> 2);
  int rb = n0 + (t >> 2);
  int ca = (t & 3) * 8;
  for (int k0 = 0; k0 < K; k0 += 32) {
    ASYNC_COPY16(&As[t * 8],        A + (size_t)ra * K + k0 + ca);
    ASYNC_COPY16(&As[2048 + t * 8], A + (size_t)(ra + 64) * K + k0 + ca);
#pragma unroll
    for (int c = 0; c < BN / 64; c++)
      ASYNC_COPY16(&Bs[c * 2048 + t * 8], Bm + (size_t)(rb + c * 64) * K + k0 + ca);
    __syncthreads();
    short8 av[4], bv[JN];
#pragma unroll
    for (int i = 0; i < 4; i++) av[i] = *(const short8*)&As[(wm + i * 16 + lr) * 32 + kb * 8];
#pragma unroll
    for (int j = 0; j < JN; j++) bv[j] = *(const short8*)&Bs[(wn + j * 16 + lr) * 32 + kb * 8];
#pragma unroll
    for (int i = 0; i < 4; i++)
#pragma unroll
      for (int j = 0; j < JN; j++)
        acc[i][j] = __builtin_amdgcn_mfma_f32_16x16x32_bf16(av[i], bv[j], acc[i][j], 0, 0, 0);
    __syncthreads();
  }
  // C/D layout: col = lane&15, row = (lane>>4)*4 + reg
#pragma unroll
  for (int i = 0; i < 4; i++) {
    int row = m0 + wm + i * 16 + kb * 4;
#pragma unroll
    for (int j = 0; j < JN; j++) {
      int col = n0 + wn + j * 16 + lr;
#pragma unroll
      for (int r = 0; r < 4; r++) {
        if (BF16OUT)
          ((unsigned short*)Cv)[(size_t)(row + r) * N + col] = f2bf(acc[i][j][r]);
        else
          ((float*)Cv)[(size_t)(row + r) * N + col] = acc[i][j][r];
      }
    }
  }
}

// ------- fused RoPE + head split (q, v, k thirds!) + V transpose, bf16 qkv in -------
// Q pre-scaled by (1/sqrt(HD)) * log2(e). Outputs: Q,K [bh][s][64],
// Vt [bh][d][s] with keys PERMUTED within each 32-tile: pos = (s&15)*2 + ((s>>4)&1)
// (matches the attention P-matrix b32 packing; P and V must agree on key order).
__global__ __launch_bounds__(256) void rope_vt(const unsigned short* __restrict__ qkv,
                                               unsigned short* __restrict__ Q,
                                               unsigned short* __restrict__ Ko,
                                               unsigned short* __restrict__ Vt) {
  __shared__ float tile[64][65];
  int t = threadIdx.x;
  int bh = blockIdx.y, s0 = blockIdx.x * 64;
  int b = bh >> 4, h = bh & 15;
  int mp = h >> 1, ii = h & 1;
  int hbase = mp * 384 + ii * 64;  // q at +0, v at +128, k at +256
  int tx = t & 63, ty = t >> 6;
#pragma unroll
  for (int q16 = 0; q16 < 16; q16++) {
    int srow = q16 * 4 + ty;
    tile[srow][tx] = bf2f(qkv[(size_t)(b * 2048 + s0 + srow) * 3072 + hbase + 128 + tx]);
  }
  // RoPE on q,k: thread t -> s row t>>2, 16-dim chunk t&3
  int sl = t >> 2, ch = t & 3;
  int s = s0 + sl;
  size_t ib = (size_t)(b * 2048 + s) * 3072 + hbase + ch * 16;
  short8 qv0 = *(const short8*)(qkv + ib);
  short8 qv1 = *(const short8*)(qkv + ib + 8);
  short8 kv0 = *(const short8*)(qkv + ib + 256);
  short8 kv1 = *(const short8*)(qkv + ib + 264);
  float qf[16], kf[16];
#pragma unroll
  for (int j = 0; j < 8; j++) {
    qf[j] = bf2f((unsigned short)qv0[j]); qf[8 + j] = bf2f((unsigned short)qv1[j]);
    kf[j] = bf2f((unsigned short)kv0[j]); kf[8 + j] = bf2f((unsigned short)kv1[j]);
  }
  if (ch < 2) {  // rotary pairs j = ch*8+jj < 16
#pragma unroll
    for (int jj = 0; jj < 8; jj++) {
      int j = ch * 8 + jj;
      float ang = (float)s * expf(-(float)j * 0.57564627324851142f);
      float sn, cs;
      sincosf(ang, &sn, &cs);
      float a = qf[2 * jj], bq = qf[2 * jj + 1];
      qf[2 * jj] = a * cs - bq * sn; qf[2 * jj + 1] = bq * cs + a * sn;
      float c2 = kf[2 * jj], d2 = kf[2 * jj + 1];
      kf[2 * jj] = c2 * cs - d2 * sn; kf[2 * jj + 1] = d2 * cs + c2 * sn;
    }
  }
  const float qs = 0.125f * 1.4426950408889634f;  // 1/sqrt(64) * log2(e)
  unsigned short qo[16], ko[16];
#pragma unroll
  for (int j = 0; j < 16; j++) { qo[j] = f2bf(qs * qf[j]); ko[j] = f2bf(kf[j]); }
  size_t ob = (size_t)(bh * 2048 + s) * 64 + ch * 16;
  *(short8*)(Q + ob) = *(short8*)qo;
  *(short8*)(Q + ob + 8) = *(short8*)(qo + 8);
  *(short8*)(Ko + ob) = *(short8*)ko;
  *(short8*)(Ko + ob + 8) = *(short8*)(ko + 8);
  __syncthreads();
#pragma unroll
  for (int q16 = 0; q16 < 16; q16++) {
    int drow = q16 * 4 + ty;
    // key permutation within each 32-key group
    int p = ((tx & 15) * 2 + ((tx >> 4) & 1)) | (tx & 32);
    Vt[(size_t)bh * 64 * 2048 + (size_t)drow * 2048 + s0 + p] = f2bf(tile[tx][drow]);
  }
}

// ---------------- fused causal flash attention, v9 = v7 + uniform per-CU load ----
// v7 core (4 waves x 16 q-rows, 32-key tiles, dbuf async staging, 21504 B LDS,
// conflict-free layouts). NEW: gid = quarter*256 + bh*8 + z with qtile by
// quarter in {z, 31-z, z+8, 23-z} -> the 4 co-resident blocks on each CU
// (stride-256 assignment) sum to EXACTLY 132 tile-iters for every z (was
// 104-160), and they share the same bh (same K/V stream -> L2 reuse).
__global__ __launch_bounds__(256, 6) void attn_fused(const unsigned short* __restrict__ Qg,
                                                     const unsigned short* __restrict__ Kg,
                                                     const unsigned short* __restrict__ Vtg,
                                                     unsigned short* __restrict__ AO) {
  __shared__ __attribute__((aligned(16))) unsigned short Ks[2 * 2048];  // 8 KB [buf][c8][row32][8]
  __shared__ __attribute__((aligned(16))) unsigned short Vs[2 * 2048];  // 8 KB [buf][c4][d64][8]
  __shared__ __attribute__((aligned(16))) unsigned short Ps[4 * 16 * 40];  // 5 KB
  int t = threadIdx.x;
  int w = t >> 6, lane = t & 63, kb = lane >> 4, lr = lane & 15;
  int gid = blockIdx.x;
  int z = gid & 7;
  int bh = (gid >> 3) & 31;
  int quarter = gid >> 8;
  // per-CU-uniform qtile map: quarters {z, 31-z, z+8, 23-z} -> sum nkt = 132
  int qtile = (quarter == 0) ? z : (quarter == 1) ? (31 - z) : (quarter == 2) ? (z + 8) : (23 - z);
  int m0 = qtile * 64;
  const unsigned short* Qb = Qg + (size_t)bh * 2048 * 64;
  const unsigned short* Kb = Kg + (size_t)bh * 2048 * 64;
  const unsigned short* Vb = Vtg + (size_t)bh * 64 * 2048;

  // Q A-fragments straight from global: rows m0 + w*16 + lr
  short8 aq0 = *(const short8*)(Qb + (size_t)(m0 + w * 16 + lr) * 64 + kb * 8);
  short8 aq1 = *(const short8*)(Qb + (size_t)(m0 + w * 16 + lr) * 64 + 32 + kb * 8);

  v4f acc[4];
  float lp[4];
#pragma unroll
  for (int n = 0; n < 4; n++) acc[n] = (v4f){0.f, 0.f, 0.f, 0.f};
#pragma unroll
  for (int r = 0; r < 4; r++) lp[r] = 0.f;

  int nkt = 2 * qtile + 2;  // 32-key tiles
  int mrow = w * 16 + kb * 4;  // this lane's first q-row (local)

  // stage K/V 32-key tile kt into buffer buf (dense lane-ordered, 1 slot each)
  int kc = t >> 5, krow_s = t & 31;   // K: slot = c*32+row
  int vc = t >> 6, vd = t & 63;       // V: slot = c*64+d
  auto stage = [&](int kt, int buf) {
    int base = buf * 2048;
    ASYNC_COPY16(&Ks[base + t * 8], Kb + (size_t)(kt * 32 + krow_s) * 64 + kc * 8);
    ASYNC_COPY16(&Vs[base + t * 8], Vb + (size_t)vd * 2048 + kt * 32 + vc * 8);
  };

  stage(0, 0);
  __syncthreads();

  unsigned short* Pw = &Ps[w * 640];  // 16 rows x stride 40
  for (int kt = 0; kt < nkt; kt++) {
    int cur = (kt & 1) * 2048;
    if (kt + 1 < nkt) stage(kt + 1, (kt + 1) & 1);  // prefetch overlaps compute
    // ---- QK^T: 16 q-rows x 32 keys per wave ----
    v4f sc[2];
#pragma unroll
    for (int n2 = 0; n2 < 2; n2++) {
      int krow = n2 * 16 + lr;
      short8 bk0 = *(const short8*)&Ks[cur + (kb * 32 + krow) * 8];
      short8 bk1 = *(const short8*)&Ks[cur + ((kb + 4) * 32 + krow) * 8];
      v4f zz = (v4f){0.f, 0.f, 0.f, 0.f};
      zz = __builtin_amdgcn_mfma_f32_16x16x32_bf16(aq0, bk0, zz, 0, 0, 0);
      zz = __builtin_amdgcn_mfma_f32_16x16x32_bf16(aq1, bk1, zz, 0, 0, 0);
      sc[n2] = zz;
    }
    if (kt >= 2 * qtile) {  // tiles overlapping the diagonal: causal mask
#pragma unroll
      for (int n2 = 0; n2 < 2; n2++)
#pragma unroll
        for (int r = 0; r < 4; r++) {
          int key = kt * 32 + n2 * 16 + lr;
          if (key > m0 + mrow + r) sc[n2][r] = -1e30f;
        }
    }
    // ---- softmax numerators, packed b32 P store (permuted key order) ----
#pragma unroll
    for (int r = 0; r < 4; r++) {
      float p0 = exp2f(sc[0][r]);
      float p1 = exp2f(sc[1][r]);
      lp[r] += p0 + p1;
      __hip_bfloat162 pb = __float22bfloat162_rn(float2{p0, p1});
      *(__hip_bfloat162*)&Pw[(mrow & 15) * 40 + r * 40 + lr * 2] = pb;
    }
    // ---- PV over 32 permuted keys (per-wave P; same-wave DS ordering) ----
    short8 ap = *(const short8*)&Pw[lr * 40 + kb * 8];
#pragma unroll
    for (int dt = 0; dt < 4; dt++) {
      int d = dt * 16 + lr;
      short8 bv = *(const short8*)&Vs[cur + (kb * 64 + d) * 8];
      acc[dt] = __builtin_amdgcn_mfma_f32_16x16x32_bf16(ap, bv, acc[dt], 0, 0, 0);
    }
    __syncthreads();  // all waves done with cur; prefetch drained
  }
  // deferred l reduction (16 lanes share a row) + output
  int b = bh >> 4, h = bh & 15;
#pragma unroll
  for (int r = 0; r < 4; r++) {
    float s = lp[r];
#pragma unroll
    for (int off = 1; off < 16; off <<= 1) s += __shfl_xor(s, off);
    float inv = 1.0f / s;
    int qrow = m0 + mrow + r;
#pragma unroll
    for (int dt = 0; dt < 4; dt++)
      AO[(size_t)(b * 2048 + qrow) * 1024 + h * 64 + dt * 16 + lr] = f2bf(acc[dt][r] * inv);
  }
}

extern "C" void kernel_launch(void* const* d_in, const int* in_sizes, int n_in,
                              void* d_out, int out_size, void* d_ws, size_t ws_size,
                              hipStream_t stream) {
  const float* hidden = (const float*)d_in[0];
  const float* w_qkv = (const float*)d_in[1];
  const float* w_out = (const float*)d_in[2];
  float* out = (float*)d_out;
  char* ws = (char*)d_ws;
  unsigned short* hid_bf = (unsigned short*)(ws);                  //  8 MB
  unsigned short* wqkv_bf = (unsigned short*)(ws + (8ull << 20));  //  6 MB
  unsigned short* wout_bf = (unsigned short*)(ws + (14ull << 20)); //  2 MB
  unsigned short* qkv_bf = (unsigned short*)(ws + (16ull << 20));  // 24 MB
  unsigned short* Qb = (unsigned short*)(ws + (40ull << 20));      //  8 MB
  unsigned short* Kb = (unsigned short*)(ws + (48ull << 20));      //  8 MB
  unsigned short* Vt = (unsigned short*)(ws + (56ull << 20));      //  8 MB
  unsigned short* AO = (unsigned short*)(ws + (64ull << 20));      //  8 MB

  convert_all<<<8192, 256, 0, stream>>>(hidden, w_qkv, w_out, hid_bf, wqkv_bf, wout_bf);
  // qkv = hidden @ w_qkv.T  (M=4096, N=3072, K=1024), bf16 out
  gemm_bt<128, true><<<dim3(24, 32), 256, 0, stream>>>(hid_bf, wqkv_bf, qkv_bf, 4096, 3072, 1024);
  rope_vt<<<dim3(32, 32), 256, 0, stream>>>(qkv_bf, Qb, Kb, Vt);
  attn_fused<<<1024, 256, 0, stream>>>(Qb, Kb, Vt, AO);
  // out = attn_out @ w_out.T  (M=4096, N=1024, K=1024), fp32 out, 128x64 tiles
  gemm_bt<64, false><<<dim3(16, 32), 256, 0, stream>>>(AO, wout_bf, out, 4096, 1024, 1024);
}